// Round 4
// baseline (226.743 us; speedup 1.0000x reference)
//
#include <hip/hip_runtime.h>
#include <cmath>

#define N_NODES 50000
#define N_EDGES 800000
#define NBUCK 196          // buckets of 256 nodes: bucket = dst >> 8
#define NHB 196            // histogram blocks, 4096 edges each
#define EPB 4096
// IN_DIM = HEADS*HID = 128, HEADS=4, HID=32

typedef unsigned short u16;
typedef unsigned int u32;
typedef unsigned char u8;
typedef __attribute__((ext_vector_type(8))) short bf16x8;
typedef __attribute__((ext_vector_type(4))) float f32x4;

static __device__ __forceinline__ float lrelu(float x) { return x > 0.f ? x : 0.2f * x; }
static __device__ __forceinline__ u16 f2bf(float f) {
    u32 b = __float_as_uint(f);
    return (u16)((b + 0x7FFFu + ((b >> 16) & 1u)) >> 16);  // RNE
}
static __device__ __forceinline__ u32 pack2(float a, float b) {
    return (u32)f2bf(a) | ((u32)f2bf(b) << 16);
}
// unsigned byte k of u -> float (compiles to v_cvt_f32_ubyte{k}: 1 VALU op vs 2 for signed)
static __device__ __forceinline__ float ub(u32 u, int k) {
    return (float)((u >> (k * 8)) & 0xffu);
}

// ---------------- CSR build stage 1 + weight pre-pack (fused dispatch) ----------------
__global__ __launch_bounds__(1024) void bhist_pack_k(const int* __restrict__ dst, u32* __restrict__ bcnt,
                                                     const float* __restrict__ W1, const float* __restrict__ W2,
                                                     u16* __restrict__ Wp1, u16* __restrict__ Wp2,
                                                     u32* __restrict__ done) {
    int tid = threadIdx.x;
    if (blockIdx.x < NHB) {
        __shared__ u32 hist[NBUCK];
        for (int i = tid; i < NBUCK; i += 1024) hist[i] = 0;
        __syncthreads();
        int base = blockIdx.x * EPB;
#pragma unroll
        for (int k = 0; k < 4; ++k) {
            int e = base + k * 1024 + tid;
            if (e < N_EDGES) atomicAdd(&hist[dst[e] >> 8], 1u);
        }
        __syncthreads();
        for (int i = tid; i < NBUCK; i += 1024) bcnt[(size_t)i * NHB + blockIdx.x] = hist[i];
    } else {
        if (blockIdx.x == NHB && tid == 0) *done = 0;   // reset last-block counter for scant_k
        int gi = (blockIdx.x - NHB) * 1024 + tid;   // 0..32767
        const float* W = (gi < 16384) ? W1 : W2;
        u16* Wp = (gi < 16384) ? Wp1 : Wp2;
        int i = gi & 16383;
        int j = i & 7, lane = (i >> 3) & 63, ks = (i >> 9) & 3, nt = i >> 11;
        int k = ks * 32 + (lane >> 4) * 8 + j;
        int ncol = nt * 16 + (lane & 15);
        Wp[i] = f2bf(W[k * 128 + ncol]);
    }
}

// 2) per-bucket exclusive scan over hist blocks + fused bucket-start scan (last block)
__global__ __launch_bounds__(256) void scant_k(const u32* __restrict__ bcnt, u32* __restrict__ wbase,
                                               u32* __restrict__ btot, int* __restrict__ bstart,
                                               u32* __restrict__ done) {
    __shared__ u32 s[256];
    __shared__ bool amLast;
    int i = blockIdx.x, t = threadIdx.x;
    u32 v = (t < NHB) ? bcnt[(size_t)i * NHB + t] : 0;
    s[t] = v;
    __syncthreads();
    for (int o = 1; o < 256; o <<= 1) {
        u32 x = (t >= o) ? s[t - o] : 0;
        __syncthreads();
        s[t] += x;
        __syncthreads();
    }
    if (t < NHB) wbase[(size_t)i * NHB + t] = s[t] - v;
    if (t == 255) atomicExch(&btot[i], s[255]);     // device-scope publish
    __threadfence();
    if (t == 0) amLast = (atomicAdd(done, 1u) == NBUCK - 1);
    __syncthreads();
    if (!amLast) return;
    __threadfence();
    u32 v2 = (t < NBUCK) ? atomicAdd(&btot[t], 0u) : 0;   // device-scope read
    s[t] = v2;
    __syncthreads();
    for (int o = 1; o < 256; o <<= 1) {
        u32 x = (t >= o) ? s[t - o] : 0;
        __syncthreads();
        s[t] += x;
        __syncthreads();
    }
    if (t < NBUCK) bstart[t] = (int)(s[t] - v2);
    if (t == NBUCK - 1) bstart[NBUCK] = (int)s[t];
}

// 3) scatter edges into bucket-contiguous array; payload = src(16b) | dst_low8(<<16)
__global__ __launch_bounds__(1024) void bscatter_k(const int* __restrict__ src, const int* __restrict__ dst,
                                                   const u32* __restrict__ wbase, const int* __restrict__ bstart,
                                                   u32* __restrict__ bucketed) {
    __shared__ u32 pos[NBUCK];
    int tid = threadIdx.x;
    for (int i = tid; i < NBUCK; i += 1024)
        pos[i] = (u32)bstart[i] + wbase[(size_t)i * NHB + blockIdx.x];
    __syncthreads();
    int base = blockIdx.x * EPB;
#pragma unroll
    for (int k = 0; k < 4; ++k) {
        int e = base + k * 1024 + tid;
        if (e < N_EDGES) {
            int d = dst[e];
            int b = d >> 8;
            u32 p = atomicAdd(&pos[b], 1u);
            bucketed[p] = (u32)src[e] | ((u32)(d & 255) << 16);
        }
    }
}

// 4) per-bucket fine CSR: node offs + u16 srcs
__global__ __launch_bounds__(1024) void bcsr_k(const u32* __restrict__ bucketed, const int* __restrict__ bstart,
                                               int* __restrict__ offs, u16* __restrict__ srcs) {
    __shared__ u32 cnt[256];
    __shared__ int s[256];
    __shared__ u32 fp[256];
    int b = blockIdx.x;
    int tid = threadIdx.x;
    int ebeg = bstart[b], eend = bstart[b + 1];
    int ne = eend - ebeg;
    if (tid < 256) cnt[tid] = 0;
    __syncthreads();
    for (int i = tid; i < ne; i += 1024)
        atomicAdd(&cnt[bucketed[ebeg + i] >> 16], 1u);
    __syncthreads();
    if (tid < 256) s[tid] = (int)cnt[tid];
    __syncthreads();
    for (int o = 1; o < 256; o <<= 1) {
        int v = (tid < 256 && tid >= o) ? s[tid - o] : 0;
        __syncthreads();
        if (tid < 256) s[tid] += v;
        __syncthreads();
    }
    if (tid < 256) {
        int excl = s[tid] - (int)cnt[tid];
        int node = b * 256 + tid;
        if (node < N_NODES) offs[node] = ebeg + excl;
        fp[tid] = (u32)excl;
    }
    if (b == NBUCK - 1 && tid == 0) offs[N_NODES] = N_EDGES;
    __syncthreads();
    for (int i = tid; i < ne; i += 1024) {
        u32 u = bucketed[ebeg + i];
        u32 p = atomicAdd(&fp[u >> 16], 1u);
        srcs[ebeg + p] = (u16)(u & 0xFFFFu);
    }
}

// ---------------- MFMA GEMM -> biased-u8 hf + fused {el,scale} float2 + er ----------------
// hq: u8 [N][128] (value+128); elhs: float2 [N][4] = {el, absmax/127}; er: fp32 [N][4].
template <int BF16IN>
__global__ __launch_bounds__(256) void gemm_mfma(
    const void* __restrict__ Xv, const u16* __restrict__ Wp,
    const float* __restrict__ al, const float* __restrict__ ar,
    u8* __restrict__ hq, float2* __restrict__ elhs, float* __restrict__ er, int n)
{
    __shared__ u16 xs[64][136];   // +8 pad: 2-way LDS bank aliasing (free)
    int row0 = blockIdx.x * 64;
    int tid = threadIdx.x;
    if (BF16IN) {
        const uint4* Xb = (const uint4*)Xv;
        for (int i = tid; i < 1024; i += 256) {
            int r = i >> 4, c = i & 15;
            uint4 v = make_uint4(0u, 0u, 0u, 0u);
            if (row0 + r < n) v = Xb[(size_t)(row0 + r) * 16 + c];
            ((uint4*)&xs[r][0])[c] = v;
        }
    } else {
        const float4* X4 = (const float4*)Xv;
        for (int i = tid; i < 2048; i += 256) {
            int r = i >> 5, c = i & 31;
            float4 v = make_float4(0.f, 0.f, 0.f, 0.f);
            if (row0 + r < n) v = X4[(size_t)(row0 + r) * 32 + c];
            ((uint2*)&xs[r][0])[c] = make_uint2(pack2(v.x, v.y), pack2(v.z, v.w));
        }
    }
    __syncthreads();

    int wave = tid >> 6, lane = tid & 63;
    int quad = lane >> 4, l15 = lane & 15;

    bf16x8 bfrag[2][4];
#pragma unroll
    for (int ct = 0; ct < 2; ++ct) {
        int nt = wave * 2 + ct;
#pragma unroll
        for (int ks = 0; ks < 4; ++ks)
            bfrag[ct][ks] = *(const bf16x8*)(Wp + ((((nt * 4 + ks) * 64) + lane) << 3));
    }

    f32x4 acc[4][2];
#pragma unroll
    for (int rt = 0; rt < 4; ++rt)
#pragma unroll
        for (int ct = 0; ct < 2; ++ct)
            acc[rt][ct] = (f32x4){0.f, 0.f, 0.f, 0.f};

#pragma unroll
    for (int ks = 0; ks < 4; ++ks) {
#pragma unroll
        for (int rt = 0; rt < 4; ++rt) {
            bf16x8 a = *(const bf16x8*)&xs[rt * 16 + l15][ks * 32 + quad * 8];
            acc[rt][0] = __builtin_amdgcn_mfma_f32_16x16x32_bf16(a, bfrag[0][ks], acc[rt][0], 0, 0, 0);
            acc[rt][1] = __builtin_amdgcn_mfma_f32_16x16x32_bf16(a, bfrag[1][ks], acc[rt][1], 0, 0, 0);
        }
    }

    float alv0 = al[wave * 32 + l15], alv1 = al[wave * 32 + 16 + l15];
    float arv0 = ar[wave * 32 + l15], arv1 = ar[wave * 32 + 16 + l15];
#pragma unroll
    for (int rt = 0; rt < 4; ++rt) {
#pragma unroll
        for (int r = 0; r < 4; ++r) {
            int row = row0 + rt * 16 + quad * 4 + r;
            float c0 = acc[rt][0][r], c1 = acc[rt][1][r];
            // per-(row, head) absmax over the wave's 32 cols (reduce over l15 lanes)
            float m = fmaxf(fabsf(c0), fabsf(c1));
            m = fmaxf(m, __shfl_xor(m, 1));
            m = fmaxf(m, __shfl_xor(m, 2));
            m = fmaxf(m, __shfl_xor(m, 4));
            m = fmaxf(m, __shfl_xor(m, 8));
            m = fmaxf(m, 1e-20f);
            float qsc = 127.0f / m;
            if (row < n) {
                hq[(size_t)row * 128 + wave * 32 + l15] = (u8)((int)rintf(c0 * qsc) + 128);
                hq[(size_t)row * 128 + wave * 32 + 16 + l15] = (u8)((int)rintf(c1 * qsc) + 128);
            }
            float pel = c0 * alv0 + c1 * alv1;
            float per = c0 * arv0 + c1 * arv1;
            pel += __shfl_xor(pel, 1); pel += __shfl_xor(pel, 2);
            pel += __shfl_xor(pel, 4); pel += __shfl_xor(pel, 8);
            per += __shfl_xor(per, 1); per += __shfl_xor(per, 2);
            per += __shfl_xor(per, 4); per += __shfl_xor(per, 8);
            if (l15 == 0 && row < n) {
                elhs[row * 4 + wave] = make_float2(pel, m * (1.0f / 127.0f));
                er[row * 4 + wave] = per;
            }
        }
    }
}

// ---------------- agg core: quarter-wave per edge, lane owns 8 biased-u8 features ----------
// Per feature: v_cvt_f32_ubyte (1 op) + FMA; bias folded out once via wss = sum(w*scale):
// sum ws*(u-128) = sum ws*u - 128*sum ws.
static __device__ __forceinline__ void agg_core(
    int node, int lane, const int* __restrict__ offs, const u16* __restrict__ srcs,
    const float2* __restrict__ elhs, const float* __restrict__ er,
    const u8* __restrict__ hq,
    float acc[8], float& den)
{
    int qw = lane >> 4;
    int q = lane & 15;
    int h = q >> 2;
    float erh = er[node * 4 + h];
    int beg = offs[node], end = offs[node + 1];
    int deg = end - beg;
    den = 0.f;
    float wss = 0.f;
#pragma unroll
    for (int i = 0; i < 8; i++) acc[i] = 0.f;

    if (deg <= 64) {
        int psrc = (lane < deg) ? (int)srcs[beg + lane] : 0;
        int base = beg;
        for (; base + 16 <= end; base += 16) {
            int j = base - beg + qw;
            int ss[4];
            ss[0] = __shfl(psrc, j);
            ss[1] = __shfl(psrc, j + 4);
            ss[2] = __shfl(psrc, j + 8);
            ss[3] = __shfl(psrc, j + 12);
            float2 eh[4];
            uint2 uv[4];
#pragma unroll
            for (int k = 0; k < 4; ++k) {
                eh[k] = elhs[ss[k] * 4 + h];
                uv[k] = *(const uint2*)(hq + (size_t)ss[k] * 128 + q * 8);
            }
#pragma unroll
            for (int k = 0; k < 4; ++k) {
                float w = __expf(lrelu(eh[k].x + erh));
                float ws = w * eh[k].y;
                den += w;
                wss += ws;
                acc[0] += ws * ub(uv[k].x, 0);
                acc[1] += ws * ub(uv[k].x, 1);
                acc[2] += ws * ub(uv[k].x, 2);
                acc[3] += ws * ub(uv[k].x, 3);
                acc[4] += ws * ub(uv[k].y, 0);
                acc[5] += ws * ub(uv[k].y, 1);
                acc[6] += ws * ub(uv[k].y, 2);
                acc[7] += ws * ub(uv[k].y, 3);
            }
        }
        for (; base + 8 <= end; base += 8) {
            int j = base - beg + qw;
            int s0 = __shfl(psrc, j);
            int s1 = __shfl(psrc, j + 4);
            float2 e0 = elhs[s0 * 4 + h], e1 = elhs[s1 * 4 + h];
            uint2 u0 = *(const uint2*)(hq + (size_t)s0 * 128 + q * 8);
            uint2 u1 = *(const uint2*)(hq + (size_t)s1 * 128 + q * 8);
            float w0 = __expf(lrelu(e0.x + erh));
            float w1 = __expf(lrelu(e1.x + erh));
            float ws0 = w0 * e0.y, ws1 = w1 * e1.y;
            den += w0 + w1;
            wss += ws0 + ws1;
            acc[0] += ws0 * ub(u0.x, 0) + ws1 * ub(u1.x, 0);
            acc[1] += ws0 * ub(u0.x, 1) + ws1 * ub(u1.x, 1);
            acc[2] += ws0 * ub(u0.x, 2) + ws1 * ub(u1.x, 2);
            acc[3] += ws0 * ub(u0.x, 3) + ws1 * ub(u1.x, 3);
            acc[4] += ws0 * ub(u0.y, 0) + ws1 * ub(u1.y, 0);
            acc[5] += ws0 * ub(u0.y, 1) + ws1 * ub(u1.y, 1);
            acc[6] += ws0 * ub(u0.y, 2) + ws1 * ub(u1.y, 2);
            acc[7] += ws0 * ub(u0.y, 3) + ws1 * ub(u1.y, 3);
        }
        for (; base < end; base += 4) {
            int e = base + qw;
            bool valid = e < end;
            int j = valid ? (e - beg) : 0;
            int s = __shfl(psrc, j);
            float2 eh = elhs[s * 4 + h];
            float w = valid ? __expf(lrelu(eh.x + erh)) : 0.f;
            float ws = w * eh.y;
            uint2 u = *(const uint2*)(hq + (size_t)s * 128 + q * 8);
            den += w;
            wss += ws;
            acc[0] += ws * ub(u.x, 0);
            acc[1] += ws * ub(u.x, 1);
            acc[2] += ws * ub(u.x, 2);
            acc[3] += ws * ub(u.x, 3);
            acc[4] += ws * ub(u.y, 0);
            acc[5] += ws * ub(u.y, 1);
            acc[6] += ws * ub(u.y, 2);
            acc[7] += ws * ub(u.y, 3);
        }
    } else {
        for (int base = beg; base < end; base += 4) {
            int e = base + qw;
            bool valid = e < end;
            int ec = valid ? e : end - 1;
            int s = srcs[ec];
            float2 eh = elhs[s * 4 + h];
            float w = valid ? __expf(lrelu(eh.x + erh)) : 0.f;
            float ws = w * eh.y;
            uint2 u = *(const uint2*)(hq + (size_t)s * 128 + q * 8);
            den += w;
            wss += ws;
            acc[0] += ws * ub(u.x, 0);
            acc[1] += ws * ub(u.x, 1);
            acc[2] += ws * ub(u.x, 2);
            acc[3] += ws * ub(u.x, 3);
            acc[4] += ws * ub(u.y, 0);
            acc[5] += ws * ub(u.y, 1);
            acc[6] += ws * ub(u.y, 2);
            acc[7] += ws * ub(u.y, 3);
        }
    }
#pragma unroll
    for (int i = 0; i < 8; i++) {
        acc[i] += __shfl_xor(acc[i], 16);
        acc[i] += __shfl_xor(acc[i], 32);
    }
    den += __shfl_xor(den, 16);
    den += __shfl_xor(den, 32);
    wss += __shfl_xor(wss, 16);
    wss += __shfl_xor(wss, 32);
    // remove the +128 bias: sum ws*(u-128) = sum ws*u - 128*sum ws
#pragma unroll
    for (int i = 0; i < 8; i++) acc[i] -= 128.0f * wss;
}

// ---------------- layer-1 aggregation (relu, bf16 out node-major) ----------------
__global__ __launch_bounds__(256) void agg1_k(const int* __restrict__ offs, const u16* __restrict__ srcs,
                                              const float2* __restrict__ elhs, const float* __restrict__ er,
                                              const u8* __restrict__ hq,
                                              const float* __restrict__ bias, u16* __restrict__ h1) {
    int node = blockIdx.x * 4 + (threadIdx.x >> 6);
    int lane = threadIdx.x & 63;
    if (node >= N_NODES) return;
    float acc[8], den;
    agg_core(node, lane, offs, srcs, elhs, er, hq, acc, den);
    int qw = lane >> 4, q = lane & 15;
    if (qw == 0) {
        float inv = 1.0f / fmaxf(den, 1e-30f);
        float o[8];
#pragma unroll
        for (int i = 0; i < 8; i++)
            o[i] = fmaxf(acc[i] * inv + bias[q * 8 + i], 0.f);
        uint4 pk;
        pk.x = pack2(o[0], o[1]);
        pk.y = pack2(o[2], o[3]);
        pk.z = pack2(o[4], o[5]);
        pk.w = pack2(o[6], o[7]);
        *(uint4*)(h1 + (size_t)node * 128 + q * 8) = pk;
    }
}

// ---------------- layer-2 aggregation fused with head-mean/relu/proj/softmax ----------------
__global__ __launch_bounds__(256) void agg2_k(const int* __restrict__ offs, const u16* __restrict__ srcs,
                                              const float2* __restrict__ elhs, const float* __restrict__ er,
                                              const u8* __restrict__ hq,
                                              const float* __restrict__ bias,
                                              const float* __restrict__ Wout, const float* __restrict__ bout,
                                              float2* __restrict__ out) {
    int node = blockIdx.x * 4 + (threadIdx.x >> 6);
    int lane = threadIdx.x & 63;
    if (node >= N_NODES) return;
    float acc[8], den;
    agg_core(node, lane, offs, srcs, elhs, er, hq, acc, den);
    int q = lane & 15;
    float inv = 1.0f / fmaxf(den, 1e-30f);
    float o[8];
#pragma unroll
    for (int i = 0; i < 8; i++) o[i] = acc[i] * inv + bias[q * 8 + i];
    // mean over heads (head = lane bits 2,3), then relu
#pragma unroll
    for (int i = 0; i < 8; i++) {
        o[i] += __shfl_xor(o[i], 4);
        o[i] += __shfl_xor(o[i], 8);
        o[i] = fmaxf(0.25f * o[i], 0.f);
    }
    int d0 = (q & 3) * 8;
    float l0 = 0.f, l1 = 0.f;
#pragma unroll
    for (int i = 0; i < 8; i++) {
        l0 += o[i] * Wout[(d0 + i) * 2];
        l1 += o[i] * Wout[(d0 + i) * 2 + 1];
    }
    l0 += __shfl_xor(l0, 1); l0 += __shfl_xor(l0, 2);
    l1 += __shfl_xor(l1, 1); l1 += __shfl_xor(l1, 2);
    if (lane == 0) {
        l0 += bout[0];
        l1 += bout[1];
        float mx = fmaxf(l0, l1);
        float e0 = __expf(l0 - mx), e1 = __expf(l1 - mx);
        float invs = 1.f / (e0 + e1);
        out[node] = make_float2(e0 * invs, e1 * invs);
    }
}

extern "C" void kernel_launch(void* const* d_in, const int* in_sizes, int n_in,
                              void* d_out, int out_size, void* d_ws, size_t ws_size,
                              hipStream_t stream) {
    const float* in_feat = (const float*)d_in[0];
    const float* W1   = (const float*)d_in[1];
    const float* al1  = (const float*)d_in[2];
    const float* ar1  = (const float*)d_in[3];
    const float* b1   = (const float*)d_in[4];
    const float* W2   = (const float*)d_in[5];
    const float* al2  = (const float*)d_in[6];
    const float* ar2  = (const float*)d_in[7];
    const float* b2   = (const float*)d_in[8];
    const float* Wout = (const float*)d_in[9];
    const float* bout = (const float*)d_in[10];
    const int*   src  = (const int*)d_in[11];
    const int*   dst  = (const int*)d_in[12];
    float* out = (float*)d_out;

    char* ws = (char*)d_ws;
    size_t off = 0;
    auto carve = [&](size_t bytes) {
        char* p = ws + off;
        off = (off + bytes + 255) & ~(size_t)255;
        return p;
    };
    u8*    hq        = (u8*)carve((size_t)N_NODES * 128);            // biased-u8 features (both layers)
    float2* elhs     = (float2*)carve((size_t)N_NODES * 4 * 8);      // {el, scale} per (node, head)
    float* er        = (float*)carve((size_t)N_NODES * 4 * 4);
    u16*   h1        = (u16*)carve((size_t)N_NODES * 128 * 2);       // layer-1 output (bf16)
    u16*   srcs      = (u16*)carve((size_t)N_EDGES * 2);
    u32*   bucketed  = (u32*)carve((size_t)N_EDGES * 4);
    u32*   bcnt      = (u32*)carve((size_t)NBUCK * NHB * 4);         // transposed [bucket][blk]
    u32*   wbase     = (u32*)carve((size_t)NBUCK * NHB * 4);
    u32*   btot      = (u32*)carve((size_t)NBUCK * 4);
    int*   bstart    = (int*)carve((size_t)(NBUCK + 1) * 4);
    int*   offs      = (int*)carve((size_t)(N_NODES + 1) * 4);
    u16*   Wp1       = (u16*)carve((size_t)16384 * 2);
    u16*   Wp2       = (u16*)carve((size_t)16384 * 2);
    u32*   done      = (u32*)carve(256);
    (void)ws_size; (void)in_sizes; (void)n_in; (void)out_size;

    const int GB = (N_NODES + 63) / 64;          // 782
    const int AB = (N_NODES + 3) / 4;            // 12500

    // bucketed CSR build (+ fused weight pre-pack; scanb2 folded into scant via last-block)
    bhist_pack_k<<<NHB + 32, 1024, 0, stream>>>(dst, bcnt, W1, W2, Wp1, Wp2, done);
    scant_k<<<NBUCK, 256, 0, stream>>>(bcnt, wbase, btot, bstart, done);
    bscatter_k<<<NHB, 1024, 0, stream>>>(src, dst, wbase, bstart, bucketed);
    bcsr_k<<<NBUCK, 1024, 0, stream>>>(bucketed, bstart, offs, srcs);

    // layer 1
    gemm_mfma<0><<<GB, 256, 0, stream>>>(in_feat, Wp1, al1, ar1, hq, elhs, er, N_NODES);
    agg1_k<<<AB, 256, 0, stream>>>(offs, srcs, elhs, er, hq, b1, h1);

    // layer 2
    gemm_mfma<1><<<GB, 256, 0, stream>>>(h1, Wp2, al2, ar2, hq, elhs, er, N_NODES);
    agg2_k<<<AB, 256, 0, stream>>>(offs, srcs, elhs, er, hq, b2, Wout, bout, (float2*)out);
}

// Round 5
// 203.413 us; speedup vs baseline: 1.1147x; 1.1147x over previous
//
#include <hip/hip_runtime.h>
#include <cmath>

#define N_NODES 50000
#define N_EDGES 800000
#define NBUCK 196          // buckets of 256 nodes: bucket = dst >> 8
#define NHB 196            // histogram blocks, 4096 edges each
#define EPB 4096
// IN_DIM = HEADS*HID = 128, HEADS=4, HID=32

typedef unsigned short u16;
typedef unsigned int u32;
typedef __attribute__((ext_vector_type(8))) short bf16x8;
typedef __attribute__((ext_vector_type(4))) float f32x4;

static __device__ __forceinline__ float lrelu(float x) { return x > 0.f ? x : 0.2f * x; }
static __device__ __forceinline__ u16 f2bf(float f) {
    u32 b = __float_as_uint(f);
    return (u16)((b + 0x7FFFu + ((b >> 16) & 1u)) >> 16);  // RNE
}
static __device__ __forceinline__ u32 pack2(float a, float b) {
    return (u32)f2bf(a) | ((u32)f2bf(b) << 16);
}
// sign-extended byte k of u -> float
static __device__ __forceinline__ float sx(u32 u, int k) {
    return (float)((int)(u << ((3 - k) * 8)) >> 24);
}

// ---------------- CSR build stage 1 + weight pre-pack (fused dispatch) ----------------
// blocks [0, NHB): per-block histogram, transposed store bcnt[bucket][blk]
// blocks [NHB, NHB+32): pack W1/W2 (fp32 row-major) into bf16 B-fragment order
__global__ __launch_bounds__(1024) void bhist_pack_k(const int* __restrict__ dst, u32* __restrict__ bcnt,
                                                     const float* __restrict__ W1, const float* __restrict__ W2,
                                                     u16* __restrict__ Wp1, u16* __restrict__ Wp2) {
    int tid = threadIdx.x;
    if (blockIdx.x < NHB) {
        __shared__ u32 hist[NBUCK];
        for (int i = tid; i < NBUCK; i += 1024) hist[i] = 0;
        __syncthreads();
        int base = blockIdx.x * EPB;
#pragma unroll
        for (int k = 0; k < 4; ++k) {
            int e = base + k * 1024 + tid;
            if (e < N_EDGES) atomicAdd(&hist[dst[e] >> 8], 1u);
        }
        __syncthreads();
        for (int i = tid; i < NBUCK; i += 1024) bcnt[(size_t)i * NHB + blockIdx.x] = hist[i];
    } else {
        int gi = (blockIdx.x - NHB) * 1024 + tid;   // 0..32767
        const float* W = (gi < 16384) ? W1 : W2;
        u16* Wp = (gi < 16384) ? Wp1 : Wp2;
        int i = gi & 16383;
        int j = i & 7, lane = (i >> 3) & 63, ks = (i >> 9) & 3, nt = i >> 11;
        int k = ks * 32 + (lane >> 4) * 8 + j;
        int ncol = nt * 16 + (lane & 15);
        Wp[i] = f2bf(W[k * 128 + ncol]);
    }
}

// 2a) per-bucket exclusive scan over hist blocks (196 parallel blocks)
__global__ __launch_bounds__(256) void scant_k(const u32* __restrict__ bcnt, u32* __restrict__ wbase,
                                               u32* __restrict__ btot) {
    __shared__ u32 s[256];
    int i = blockIdx.x, t = threadIdx.x;
    u32 v = (t < NHB) ? bcnt[(size_t)i * NHB + t] : 0;
    s[t] = v;
    __syncthreads();
    for (int o = 1; o < 256; o <<= 1) {
        u32 x = (t >= o) ? s[t - o] : 0;
        __syncthreads();
        s[t] += x;
        __syncthreads();
    }
    if (t < NHB) wbase[(size_t)i * NHB + t] = s[t] - v;
    if (t == 255) btot[i] = s[255];
}

// 2b) bucket starts
__global__ __launch_bounds__(256) void scanb2_k(const u32* __restrict__ btot, int* __restrict__ bstart) {
    __shared__ u32 s[256];
    int t = threadIdx.x;
    u32 v = (t < NBUCK) ? btot[t] : 0;
    s[t] = v;
    __syncthreads();
    for (int o = 1; o < 256; o <<= 1) {
        u32 x = (t >= o) ? s[t - o] : 0;
        __syncthreads();
        s[t] += x;
        __syncthreads();
    }
    if (t < NBUCK) bstart[t] = (int)(s[t] - v);
    if (t == NBUCK - 1) bstart[NBUCK] = (int)s[t];
}

// 3) scatter edges into bucket-contiguous array; payload = src(16b) | dst_low8(<<16)
__global__ __launch_bounds__(1024) void bscatter_k(const int* __restrict__ src, const int* __restrict__ dst,
                                                   const u32* __restrict__ wbase, const int* __restrict__ bstart,
                                                   u32* __restrict__ bucketed) {
    __shared__ u32 pos[NBUCK];
    int tid = threadIdx.x;
    for (int i = tid; i < NBUCK; i += 1024)
        pos[i] = (u32)bstart[i] + wbase[(size_t)i * NHB + blockIdx.x];
    __syncthreads();
    int base = blockIdx.x * EPB;
#pragma unroll
    for (int k = 0; k < 4; ++k) {
        int e = base + k * 1024 + tid;
        if (e < N_EDGES) {
            int d = dst[e];
            int b = d >> 8;
            u32 p = atomicAdd(&pos[b], 1u);
            bucketed[p] = (u32)src[e] | ((u32)(d & 255) << 16);
        }
    }
}

// ---------------- 4+5 fused dispatch: bcsr (196 blocks) + layer-1 GEMM (782 blocks) --------
// bcsr (bucketed->offs/srcs) and gemm1 (in_feat@W1->hq/elhs/er) are mutually independent,
// so they share one dispatch and overlap. Both bodies are the PROVEN round-0 shapes:
// bcsr at 256 threads / 3KB LDS (aliased), gemm1 at 256 threads / 64-row tile / 17.4KB LDS.
// 8 blocks/CU -> all 978 blocks co-resident -> duration ~= max(bcsr, gemm1), not sum.
__global__ __launch_bounds__(256) void bcsr_gemm1_k(
    const u32* __restrict__ bucketed, const int* __restrict__ bstart,
    int* __restrict__ offs, u16* __restrict__ srcs,
    const float* __restrict__ X, const u16* __restrict__ Wp,
    const float* __restrict__ al, const float* __restrict__ ar,
    signed char* __restrict__ hq, float2* __restrict__ elhs, float* __restrict__ er, int n)
{
    __shared__ u16 xs[64][136];   // gemm tile; bcsr aliases its 3KB scratch on top
    int tid = threadIdx.x;

    if (blockIdx.x < NBUCK) {
        // ---- bcsr body (verbatim round-0, 256 threads) ----
        u32* cnt = (u32*)&xs[0][0];
        int* s   = (int*)(cnt + 256);
        u32* fp  = (u32*)(s + 256);
        int b = blockIdx.x;
        int ebeg = bstart[b], eend = bstart[b + 1];
        int ne = eend - ebeg;
        cnt[tid] = 0;
        __syncthreads();
        for (int i = tid; i < ne; i += 256)
            atomicAdd(&cnt[bucketed[ebeg + i] >> 16], 1u);
        __syncthreads();
        s[tid] = (int)cnt[tid];
        __syncthreads();
        for (int o = 1; o < 256; o <<= 1) {
            int v = (tid >= o) ? s[tid - o] : 0;
            __syncthreads();
            s[tid] += v;
            __syncthreads();
        }
        int excl = s[tid] - (int)cnt[tid];
        int node = b * 256 + tid;
        if (node < N_NODES) offs[node] = ebeg + excl;
        if (b == NBUCK - 1 && tid == 0) offs[N_NODES] = N_EDGES;
        fp[tid] = (u32)excl;
        __syncthreads();
        for (int i = tid; i < ne; i += 256) {
            u32 u = bucketed[ebeg + i];
            u32 p = atomicAdd(&fp[u >> 16], 1u);
            srcs[ebeg + p] = (u16)(u & 0xFFFFu);
        }
        return;
    }

    // ---- gemm1 body (verbatim round-0 gemm_mfma<0>, fp32 input) ----
    int row0 = (blockIdx.x - NBUCK) * 64;
    const float4* X4 = (const float4*)X;
    for (int i = tid; i < 2048; i += 256) {
        int r = i >> 5, c = i & 31;
        float4 v = make_float4(0.f, 0.f, 0.f, 0.f);
        if (row0 + r < n) v = X4[(size_t)(row0 + r) * 32 + c];
        ((uint2*)&xs[r][0])[c] = make_uint2(pack2(v.x, v.y), pack2(v.z, v.w));
    }
    __syncthreads();

    int wave = tid >> 6, lane = tid & 63;
    int quad = lane >> 4, l15 = lane & 15;

    bf16x8 bfrag[2][4];
#pragma unroll
    for (int ct = 0; ct < 2; ++ct) {
        int nt = wave * 2 + ct;
#pragma unroll
        for (int ks = 0; ks < 4; ++ks)
            bfrag[ct][ks] = *(const bf16x8*)(Wp + ((((nt * 4 + ks) * 64) + lane) << 3));
    }

    f32x4 acc[4][2];
#pragma unroll
    for (int rt = 0; rt < 4; ++rt)
#pragma unroll
        for (int ct = 0; ct < 2; ++ct)
            acc[rt][ct] = (f32x4){0.f, 0.f, 0.f, 0.f};

#pragma unroll
    for (int ks = 0; ks < 4; ++ks) {
#pragma unroll
        for (int rt = 0; rt < 4; ++rt) {
            bf16x8 a = *(const bf16x8*)&xs[rt * 16 + l15][ks * 32 + quad * 8];
            acc[rt][0] = __builtin_amdgcn_mfma_f32_16x16x32_bf16(a, bfrag[0][ks], acc[rt][0], 0, 0, 0);
            acc[rt][1] = __builtin_amdgcn_mfma_f32_16x16x32_bf16(a, bfrag[1][ks], acc[rt][1], 0, 0, 0);
        }
    }

    float alv0 = al[wave * 32 + l15], alv1 = al[wave * 32 + 16 + l15];
    float arv0 = ar[wave * 32 + l15], arv1 = ar[wave * 32 + 16 + l15];
#pragma unroll
    for (int rt = 0; rt < 4; ++rt) {
#pragma unroll
        for (int r = 0; r < 4; ++r) {
            int row = row0 + rt * 16 + quad * 4 + r;
            float c0 = acc[rt][0][r], c1 = acc[rt][1][r];
            float m = fmaxf(fabsf(c0), fabsf(c1));
            m = fmaxf(m, __shfl_xor(m, 1));
            m = fmaxf(m, __shfl_xor(m, 2));
            m = fmaxf(m, __shfl_xor(m, 4));
            m = fmaxf(m, __shfl_xor(m, 8));
            m = fmaxf(m, 1e-20f);
            float qsc = 127.0f / m;
            if (row < n) {
                hq[(size_t)row * 128 + wave * 32 + l15] = (signed char)(int)rintf(c0 * qsc);
                hq[(size_t)row * 128 + wave * 32 + 16 + l15] = (signed char)(int)rintf(c1 * qsc);
            }
            float pel = c0 * alv0 + c1 * alv1;
            float per = c0 * arv0 + c1 * arv1;
            pel += __shfl_xor(pel, 1); pel += __shfl_xor(pel, 2);
            pel += __shfl_xor(pel, 4); pel += __shfl_xor(pel, 8);
            per += __shfl_xor(per, 1); per += __shfl_xor(per, 2);
            per += __shfl_xor(per, 4); per += __shfl_xor(per, 8);
            if (l15 == 0 && row < n) {
                elhs[row * 4 + wave] = make_float2(pel, m * (1.0f / 127.0f));
                er[row * 4 + wave] = per;
            }
        }
    }
}

// ---------------- MFMA GEMM -> int8 hf + fused {el,scale} float2 + er (layer 2) ----------------
template <int BF16IN>
__global__ __launch_bounds__(256) void gemm_mfma(
    const void* __restrict__ Xv, const u16* __restrict__ Wp,
    const float* __restrict__ al, const float* __restrict__ ar,
    signed char* __restrict__ hq, float2* __restrict__ elhs, float* __restrict__ er, int n)
{
    __shared__ u16 xs[64][136];   // +8 pad: 2-way LDS bank aliasing (free)
    int row0 = blockIdx.x * 64;
    int tid = threadIdx.x;
    if (BF16IN) {
        const uint4* Xb = (const uint4*)Xv;
        for (int i = tid; i < 1024; i += 256) {
            int r = i >> 4, c = i & 15;
            uint4 v = make_uint4(0u, 0u, 0u, 0u);
            if (row0 + r < n) v = Xb[(size_t)(row0 + r) * 16 + c];
            ((uint4*)&xs[r][0])[c] = v;
        }
    } else {
        const float4* X4 = (const float4*)Xv;
        for (int i = tid; i < 2048; i += 256) {
            int r = i >> 5, c = i & 31;
            float4 v = make_float4(0.f, 0.f, 0.f, 0.f);
            if (row0 + r < n) v = X4[(size_t)(row0 + r) * 32 + c];
            ((uint2*)&xs[r][0])[c] = make_uint2(pack2(v.x, v.y), pack2(v.z, v.w));
        }
    }
    __syncthreads();

    int wave = tid >> 6, lane = tid & 63;
    int quad = lane >> 4, l15 = lane & 15;

    bf16x8 bfrag[2][4];
#pragma unroll
    for (int ct = 0; ct < 2; ++ct) {
        int nt = wave * 2 + ct;
#pragma unroll
        for (int ks = 0; ks < 4; ++ks)
            bfrag[ct][ks] = *(const bf16x8*)(Wp + ((((nt * 4 + ks) * 64) + lane) << 3));
    }

    f32x4 acc[4][2];
#pragma unroll
    for (int rt = 0; rt < 4; ++rt)
#pragma unroll
        for (int ct = 0; ct < 2; ++ct)
            acc[rt][ct] = (f32x4){0.f, 0.f, 0.f, 0.f};

#pragma unroll
    for (int ks = 0; ks < 4; ++ks) {
#pragma unroll
        for (int rt = 0; rt < 4; ++rt) {
            bf16x8 a = *(const bf16x8*)&xs[rt * 16 + l15][ks * 32 + quad * 8];
            acc[rt][0] = __builtin_amdgcn_mfma_f32_16x16x32_bf16(a, bfrag[0][ks], acc[rt][0], 0, 0, 0);
            acc[rt][1] = __builtin_amdgcn_mfma_f32_16x16x32_bf16(a, bfrag[1][ks], acc[rt][1], 0, 0, 0);
        }
    }

    float alv0 = al[wave * 32 + l15], alv1 = al[wave * 32 + 16 + l15];
    float arv0 = ar[wave * 32 + l15], arv1 = ar[wave * 32 + 16 + l15];
#pragma unroll
    for (int rt = 0; rt < 4; ++rt) {
#pragma unroll
        for (int r = 0; r < 4; ++r) {
            int row = row0 + rt * 16 + quad * 4 + r;
            float c0 = acc[rt][0][r], c1 = acc[rt][1][r];
            // per-(row, head) absmax over the wave's 32 cols (reduce over l15 lanes)
            float m = fmaxf(fabsf(c0), fabsf(c1));
            m = fmaxf(m, __shfl_xor(m, 1));
            m = fmaxf(m, __shfl_xor(m, 2));
            m = fmaxf(m, __shfl_xor(m, 4));
            m = fmaxf(m, __shfl_xor(m, 8));
            m = fmaxf(m, 1e-20f);
            float qsc = 127.0f / m;
            if (row < n) {
                hq[(size_t)row * 128 + wave * 32 + l15] = (signed char)(int)rintf(c0 * qsc);
                hq[(size_t)row * 128 + wave * 32 + 16 + l15] = (signed char)(int)rintf(c1 * qsc);
            }
            float pel = c0 * alv0 + c1 * alv1;
            float per = c0 * arv0 + c1 * arv1;
            pel += __shfl_xor(pel, 1); pel += __shfl_xor(pel, 2);
            pel += __shfl_xor(pel, 4); pel += __shfl_xor(pel, 8);
            per += __shfl_xor(per, 1); per += __shfl_xor(per, 2);
            per += __shfl_xor(per, 4); per += __shfl_xor(per, 8);
            if (l15 == 0 && row < n) {
                elhs[row * 4 + wave] = make_float2(pel, m * (1.0f / 127.0f));
                er[row * 4 + wave] = per;
            }
        }
    }
}

// ---------------- agg core: quarter-wave per edge, lane owns 8 int8 features (uint2) ---------
// Two gather streams per edge: elhs (8B) + hq (8B). srcs preloaded via one coalesced load+shfl.
static __device__ __forceinline__ void agg_core(
    int node, int lane, const int* __restrict__ offs, const u16* __restrict__ srcs,
    const float2* __restrict__ elhs, const float* __restrict__ er,
    const signed char* __restrict__ hq,
    float acc[8], float& den)
{
    int qw = lane >> 4;
    int q = lane & 15;
    int h = q >> 2;
    float erh = er[node * 4 + h];
    int beg = offs[node], end = offs[node + 1];
    int deg = end - beg;
    den = 0.f;
#pragma unroll
    for (int i = 0; i < 8; i++) acc[i] = 0.f;

    if (deg <= 64) {
        int psrc = (lane < deg) ? (int)srcs[beg + lane] : 0;
        int base = beg;
        for (; base + 16 <= end; base += 16) {
            int j = base - beg + qw;
            int ss[4];
            ss[0] = __shfl(psrc, j);
            ss[1] = __shfl(psrc, j + 4);
            ss[2] = __shfl(psrc, j + 8);
            ss[3] = __shfl(psrc, j + 12);
            float2 eh[4];
            uint2 uv[4];
#pragma unroll
            for (int k = 0; k < 4; ++k) {
                eh[k] = elhs[ss[k] * 4 + h];
                uv[k] = *(const uint2*)(hq + (size_t)ss[k] * 128 + q * 8);
            }
#pragma unroll
            for (int k = 0; k < 4; ++k) {
                float w = __expf(lrelu(eh[k].x + erh));
                float ws = w * eh[k].y;
                den += w;
                acc[0] += ws * sx(uv[k].x, 0);
                acc[1] += ws * sx(uv[k].x, 1);
                acc[2] += ws * sx(uv[k].x, 2);
                acc[3] += ws * sx(uv[k].x, 3);
                acc[4] += ws * sx(uv[k].y, 0);
                acc[5] += ws * sx(uv[k].y, 1);
                acc[6] += ws * sx(uv[k].y, 2);
                acc[7] += ws * sx(uv[k].y, 3);
            }
        }
        for (; base + 8 <= end; base += 8) {
            int j = base - beg + qw;
            int s0 = __shfl(psrc, j);
            int s1 = __shfl(psrc, j + 4);
            float2 e0 = elhs[s0 * 4 + h], e1 = elhs[s1 * 4 + h];
            uint2 u0 = *(const uint2*)(hq + (size_t)s0 * 128 + q * 8);
            uint2 u1 = *(const uint2*)(hq + (size_t)s1 * 128 + q * 8);
            float w0 = __expf(lrelu(e0.x + erh));
            float w1 = __expf(lrelu(e1.x + erh));
            float ws0 = w0 * e0.y, ws1 = w1 * e1.y;
            den += w0 + w1;
            acc[0] += ws0 * sx(u0.x, 0) + ws1 * sx(u1.x, 0);
            acc[1] += ws0 * sx(u0.x, 1) + ws1 * sx(u1.x, 1);
            acc[2] += ws0 * sx(u0.x, 2) + ws1 * sx(u1.x, 2);
            acc[3] += ws0 * sx(u0.x, 3) + ws1 * sx(u1.x, 3);
            acc[4] += ws0 * sx(u0.y, 0) + ws1 * sx(u1.y, 0);
            acc[5] += ws0 * sx(u0.y, 1) + ws1 * sx(u1.y, 1);
            acc[6] += ws0 * sx(u0.y, 2) + ws1 * sx(u1.y, 2);
            acc[7] += ws0 * sx(u0.y, 3) + ws1 * sx(u1.y, 3);
        }
        for (; base < end; base += 4) {
            int e = base + qw;
            bool valid = e < end;
            int j = valid ? (e - beg) : 0;
            int s = __shfl(psrc, j);
            float2 eh = elhs[s * 4 + h];
            float w = valid ? __expf(lrelu(eh.x + erh)) : 0.f;
            float ws = w * eh.y;
            uint2 u = *(const uint2*)(hq + (size_t)s * 128 + q * 8);
            den += w;
            acc[0] += ws * sx(u.x, 0);
            acc[1] += ws * sx(u.x, 1);
            acc[2] += ws * sx(u.x, 2);
            acc[3] += ws * sx(u.x, 3);
            acc[4] += ws * sx(u.y, 0);
            acc[5] += ws * sx(u.y, 1);
            acc[6] += ws * sx(u.y, 2);
            acc[7] += ws * sx(u.y, 3);
        }
    } else {
        for (int base = beg; base < end; base += 4) {
            int e = base + qw;
            bool valid = e < end;
            int ec = valid ? e : end - 1;
            int s = srcs[ec];
            float2 eh = elhs[s * 4 + h];
            float w = valid ? __expf(lrelu(eh.x + erh)) : 0.f;
            float ws = w * eh.y;
            uint2 u = *(const uint2*)(hq + (size_t)s * 128 + q * 8);
            den += w;
            acc[0] += ws * sx(u.x, 0);
            acc[1] += ws * sx(u.x, 1);
            acc[2] += ws * sx(u.x, 2);
            acc[3] += ws * sx(u.x, 3);
            acc[4] += ws * sx(u.y, 0);
            acc[5] += ws * sx(u.y, 1);
            acc[6] += ws * sx(u.y, 2);
            acc[7] += ws * sx(u.y, 3);
        }
    }
#pragma unroll
    for (int i = 0; i < 8; i++) {
        acc[i] += __shfl_xor(acc[i], 16);
        acc[i] += __shfl_xor(acc[i], 32);
    }
    den += __shfl_xor(den, 16);
    den += __shfl_xor(den, 32);
}

// ---------------- layer-1 aggregation (relu, bf16 out node-major) ----------------
__global__ __launch_bounds__(256) void agg1_k(const int* __restrict__ offs, const u16* __restrict__ srcs,
                                              const float2* __restrict__ elhs, const float* __restrict__ er,
                                              const signed char* __restrict__ hq,
                                              const float* __restrict__ bias, u16* __restrict__ h1) {
    int node = blockIdx.x * 4 + (threadIdx.x >> 6);
    int lane = threadIdx.x & 63;
    if (node >= N_NODES) return;
    float acc[8], den;
    agg_core(node, lane, offs, srcs, elhs, er, hq, acc, den);
    int qw = lane >> 4, q = lane & 15;
    if (qw == 0) {
        float inv = 1.0f / fmaxf(den, 1e-30f);
        float o[8];
#pragma unroll
        for (int i = 0; i < 8; i++)
            o[i] = fmaxf(acc[i] * inv + bias[q * 8 + i], 0.f);
        uint4 pk;
        pk.x = pack2(o[0], o[1]);
        pk.y = pack2(o[2], o[3]);
        pk.z = pack2(o[4], o[5]);
        pk.w = pack2(o[6], o[7]);
        *(uint4*)(h1 + (size_t)node * 128 + q * 8) = pk;
    }
}

// ---------------- layer-2 aggregation fused with head-mean/relu/proj/softmax ----------------
__global__ __launch_bounds__(256) void agg2_k(const int* __restrict__ offs, const u16* __restrict__ srcs,
                                              const float2* __restrict__ elhs, const float* __restrict__ er,
                                              const signed char* __restrict__ hq,
                                              const float* __restrict__ bias,
                                              const float* __restrict__ Wout, const float* __restrict__ bout,
                                              float2* __restrict__ out) {
    int node = blockIdx.x * 4 + (threadIdx.x >> 6);
    int lane = threadIdx.x & 63;
    if (node >= N_NODES) return;
    float acc[8], den;
    agg_core(node, lane, offs, srcs, elhs, er, hq, acc, den);
    int q = lane & 15;
    float inv = 1.0f / fmaxf(den, 1e-30f);
    float o[8];
#pragma unroll
    for (int i = 0; i < 8; i++) o[i] = acc[i] * inv + bias[q * 8 + i];
    // mean over heads (head = lane bits 2,3), then relu
#pragma unroll
    for (int i = 0; i < 8; i++) {
        o[i] += __shfl_xor(o[i], 4);
        o[i] += __shfl_xor(o[i], 8);
        o[i] = fmaxf(0.25f * o[i], 0.f);
    }
    int d0 = (q & 3) * 8;
    float l0 = 0.f, l1 = 0.f;
#pragma unroll
    for (int i = 0; i < 8; i++) {
        l0 += o[i] * Wout[(d0 + i) * 2];
        l1 += o[i] * Wout[(d0 + i) * 2 + 1];
    }
    l0 += __shfl_xor(l0, 1); l0 += __shfl_xor(l0, 2);
    l1 += __shfl_xor(l1, 1); l1 += __shfl_xor(l1, 2);
    if (lane == 0) {
        l0 += bout[0];
        l1 += bout[1];
        float mx = fmaxf(l0, l1);
        float e0 = __expf(l0 - mx), e1 = __expf(l1 - mx);
        float invs = 1.f / (e0 + e1);
        out[node] = make_float2(e0 * invs, e1 * invs);
    }
}

extern "C" void kernel_launch(void* const* d_in, const int* in_sizes, int n_in,
                              void* d_out, int out_size, void* d_ws, size_t ws_size,
                              hipStream_t stream) {
    const float* in_feat = (const float*)d_in[0];
    const float* W1   = (const float*)d_in[1];
    const float* al1  = (const float*)d_in[2];
    const float* ar1  = (const float*)d_in[3];
    const float* b1   = (const float*)d_in[4];
    const float* W2   = (const float*)d_in[5];
    const float* al2  = (const float*)d_in[6];
    const float* ar2  = (const float*)d_in[7];
    const float* b2   = (const float*)d_in[8];
    const float* Wout = (const float*)d_in[9];
    const float* bout = (const float*)d_in[10];
    const int*   src  = (const int*)d_in[11];
    const int*   dst  = (const int*)d_in[12];
    float* out = (float*)d_out;

    char* ws = (char*)d_ws;
    size_t off = 0;
    auto carve = [&](size_t bytes) {
        char* p = ws + off;
        off = (off + bytes + 255) & ~(size_t)255;
        return p;
    };
    signed char* hq  = (signed char*)carve((size_t)N_NODES * 128);   // int8 features
    float2* elhs     = (float2*)carve((size_t)N_NODES * 4 * 8);      // {el, scale} per (node, head)
    u16*   h1        = (u16*)carve((size_t)N_NODES * 128 * 2);       // layer-1 output (bf16)
    float* er        = (float*)carve((size_t)N_NODES * 4 * 4);
    u16*   srcs      = (u16*)carve((size_t)N_EDGES * 2);
    u32*   bucketed  = (u32*)carve((size_t)N_EDGES * 4);
    u32*   bcnt      = (u32*)carve((size_t)NBUCK * NHB * 4);         // transposed [bucket][blk]
    u32*   wbase     = (u32*)carve((size_t)NBUCK * NHB * 4);
    u32*   btot      = (u32*)carve((size_t)NBUCK * 4);
    int*   bstart    = (int*)carve((size_t)(NBUCK + 1) * 4);
    int*   offs      = (int*)carve((size_t)(N_NODES + 1) * 4);
    u16*   Wp1       = (u16*)carve((size_t)16384 * 2);
    u16*   Wp2       = (u16*)carve((size_t)16384 * 2);
    (void)ws_size; (void)in_sizes; (void)n_in; (void)out_size;

    const int GB = (N_NODES + 63) / 64;          // 782
    const int AB = (N_NODES + 3) / 4;            // 12500

    // bucketed CSR build (+ fused weight pre-pack)
    bhist_pack_k<<<NHB + 32, 1024, 0, stream>>>(dst, bcnt, W1, W2, Wp1, Wp2);
    scant_k<<<NBUCK, 256, 0, stream>>>(bcnt, wbase, btot);
    scanb2_k<<<1, 256, 0, stream>>>(btot, bstart);
    bscatter_k<<<NHB, 1024, 0, stream>>>(src, dst, wbase, bstart, bucketed);

    // fine CSR + layer-1 GEMM overlapped in one dispatch (independent work, proven shapes)
    bcsr_gemm1_k<<<NBUCK + GB, 256, 0, stream>>>(bucketed, bstart, offs, srcs,
                                                 in_feat, Wp1, al1, ar1, hq, elhs, er, N_NODES);

    // layer 1 aggregation
    agg1_k<<<AB, 256, 0, stream>>>(offs, srcs, elhs, er, hq, b1, h1);

    // layer 2
    gemm_mfma<1><<<GB, 256, 0, stream>>>(h1, Wp2, al2, ar2, hq, elhs, er, N_NODES);
    agg2_k<<<AB, 256, 0, stream>>>(offs, srcs, elhs, er, hq, b2, Wout, bout, (float2*)out);
}

// Round 6
// 200.041 us; speedup vs baseline: 1.1335x; 1.0169x over previous
//
#include <hip/hip_runtime.h>
#include <cmath>

#define N_NODES 50000
#define N_EDGES 800000
#define NBUCK 196          // buckets of 256 nodes: bucket = dst >> 8
#define EPB 4096           // edges per scatter block
#define CAP 5120           // per-bucket capacity (mean 4096, sigma 64 -> +16 sigma)
// IN_DIM = HEADS*HID = 128, HEADS=4, HID=32

typedef unsigned short u16;
typedef unsigned int u32;
typedef __attribute__((ext_vector_type(8))) short bf16x8;
typedef __attribute__((ext_vector_type(4))) float f32x4;

static __device__ __forceinline__ float lrelu(float x) { return x > 0.f ? x : 0.2f * x; }
static __device__ __forceinline__ u16 f2bf(float f) {
    u32 b = __float_as_uint(f);
    return (u16)((b + 0x7FFFu + ((b >> 16) & 1u)) >> 16);  // RNE
}
static __device__ __forceinline__ u32 pack2(float a, float b) {
    return (u32)f2bf(a) | ((u32)f2bf(b) << 16);
}
// sign-extended byte k of u -> float
static __device__ __forceinline__ float sx(u32 u, int k) {
    return (float)((int)(u << ((3 - k) * 8)) >> 24);
}

// ---------------- D1: weight pre-pack (32 blocks) + gpos zero (1 block) ----------------
__global__ __launch_bounds__(1024) void pack_zero_k(const float* __restrict__ W1, const float* __restrict__ W2,
                                                    u16* __restrict__ Wp1, u16* __restrict__ Wp2,
                                                    u32* __restrict__ gpos) {
    int tid = threadIdx.x;
    if (blockIdx.x == 32) {
        if (tid < NBUCK) gpos[tid] = 0;
        return;
    }
    int gi = blockIdx.x * 1024 + tid;   // 0..32767
    const float* W = (gi < 16384) ? W1 : W2;
    u16* Wp = (gi < 16384) ? Wp1 : Wp2;
    int i = gi & 16383;
    int j = i & 7, lane = (i >> 3) & 63, ks = (i >> 9) & 3, nt = i >> 11;
    int k = ks * 32 + (lane >> 4) * 8 + j;
    int ncol = nt * 16 + (lane & 15);
    Wp[i] = f2bf(W[k * 128 + ncol]);
}

// ---------------- D2: one-pass scatter with atomic block reservation ----------------
// Each block: LDS-histogram its 4096 edges (src/dst stashed in registers -> one global
// pass), reserve per-bucket ranges via atomicAdd(gpos[b], cnt), scatter into the
// fixed-capacity padded bucket slots. Replaces bhist/scant/scanb2/bscatter (4 dispatches).
__global__ __launch_bounds__(1024) void bscatter2_k(const int* __restrict__ src, const int* __restrict__ dst,
                                                    u32* __restrict__ gpos, u32* __restrict__ bucketed) {
    __shared__ u32 hist[NBUCK];
    __shared__ u32 lpos[NBUCK];
    int tid = threadIdx.x;
    for (int i = tid; i < NBUCK; i += 1024) hist[i] = 0;
    __syncthreads();
    int base = blockIdx.x * EPB;
    int ss[4], dd[4];
#pragma unroll
    for (int k = 0; k < 4; ++k) {
        int e = base + k * 1024 + tid;
        bool v = e < N_EDGES;
        ss[k] = v ? src[e] : 0;
        dd[k] = v ? dst[e] : -1;
        if (v) atomicAdd(&hist[dd[k] >> 8], 1u);
    }
    __syncthreads();
    for (int i = tid; i < NBUCK; i += 1024) {
        u32 c = hist[i];
        lpos[i] = c ? atomicAdd(&gpos[i], c) : 0u;
    }
    __syncthreads();
#pragma unroll
    for (int k = 0; k < 4; ++k) {
        if (dd[k] >= 0) {
            int b = dd[k] >> 8;
            u32 p = atomicAdd(&lpos[b], 1u);
            if (p < CAP) bucketed[(size_t)b * CAP + p] = (u32)ss[k] | ((u32)(dd[k] & 255) << 16);
        }
    }
}

// ---------------- D3: bcsr (196 blocks) + layer-1 GEMM (782 blocks) fused ----------
// Proven round-5 structure; bcsr now reads counts from gpos and writes offs2 {beg,end}.
__global__ __launch_bounds__(256) void bcsr_gemm1_k(
    const u32* __restrict__ bucketed, const u32* __restrict__ gpos,
    int2* __restrict__ offs2, u16* __restrict__ srcs,
    const float* __restrict__ X, const u16* __restrict__ Wp,
    const float* __restrict__ al, const float* __restrict__ ar,
    signed char* __restrict__ hq, float2* __restrict__ elhs, float* __restrict__ er, int n)
{
    __shared__ u16 xs[64][136];   // gemm tile; bcsr aliases its 3KB scratch on top
    int tid = threadIdx.x;

    if (blockIdx.x < NBUCK) {
        // ---- bcsr body (per-bucket fine CSR: node offs2 + u16 srcs) ----
        u32* cnt = (u32*)&xs[0][0];
        int* s   = (int*)(cnt + 256);
        u32* fp  = (u32*)(s + 256);
        int b = blockIdx.x;
        int ebeg = b * CAP;
        int ne = (int)gpos[b];
        if (ne > CAP) ne = CAP;
        cnt[tid] = 0;
        __syncthreads();
        for (int i = tid; i < ne; i += 256)
            atomicAdd(&cnt[bucketed[ebeg + i] >> 16], 1u);
        __syncthreads();
        s[tid] = (int)cnt[tid];
        __syncthreads();
        for (int o = 1; o < 256; o <<= 1) {
            int v = (tid >= o) ? s[tid - o] : 0;
            __syncthreads();
            s[tid] += v;
            __syncthreads();
        }
        int excl = s[tid] - (int)cnt[tid];
        int node = b * 256 + tid;
        if (node < N_NODES) offs2[node] = make_int2(ebeg + excl, ebeg + excl + (int)cnt[tid]);
        fp[tid] = (u32)excl;
        __syncthreads();
        for (int i = tid; i < ne; i += 256) {
            u32 u = bucketed[ebeg + i];
            u32 p = atomicAdd(&fp[u >> 16], 1u);
            srcs[ebeg + p] = (u16)(u & 0xFFFFu);
        }
        return;
    }

    // ---- gemm1 body (verbatim round-5, fp32 input) ----
    int row0 = (blockIdx.x - NBUCK) * 64;
    const float4* X4 = (const float4*)X;
    for (int i = tid; i < 2048; i += 256) {
        int r = i >> 5, c = i & 31;
        float4 v = make_float4(0.f, 0.f, 0.f, 0.f);
        if (row0 + r < n) v = X4[(size_t)(row0 + r) * 32 + c];
        ((uint2*)&xs[r][0])[c] = make_uint2(pack2(v.x, v.y), pack2(v.z, v.w));
    }
    __syncthreads();

    int wave = tid >> 6, lane = tid & 63;
    int quad = lane >> 4, l15 = lane & 15;

    bf16x8 bfrag[2][4];
#pragma unroll
    for (int ct = 0; ct < 2; ++ct) {
        int nt = wave * 2 + ct;
#pragma unroll
        for (int ks = 0; ks < 4; ++ks)
            bfrag[ct][ks] = *(const bf16x8*)(Wp + ((((nt * 4 + ks) * 64) + lane) << 3));
    }

    f32x4 acc[4][2];
#pragma unroll
    for (int rt = 0; rt < 4; ++rt)
#pragma unroll
        for (int ct = 0; ct < 2; ++ct)
            acc[rt][ct] = (f32x4){0.f, 0.f, 0.f, 0.f};

#pragma unroll
    for (int ks = 0; ks < 4; ++ks) {
#pragma unroll
        for (int rt = 0; rt < 4; ++rt) {
            bf16x8 a = *(const bf16x8*)&xs[rt * 16 + l15][ks * 32 + quad * 8];
            acc[rt][0] = __builtin_amdgcn_mfma_f32_16x16x32_bf16(a, bfrag[0][ks], acc[rt][0], 0, 0, 0);
            acc[rt][1] = __builtin_amdgcn_mfma_f32_16x16x32_bf16(a, bfrag[1][ks], acc[rt][1], 0, 0, 0);
        }
    }

    float alv0 = al[wave * 32 + l15], alv1 = al[wave * 32 + 16 + l15];
    float arv0 = ar[wave * 32 + l15], arv1 = ar[wave * 32 + 16 + l15];
#pragma unroll
    for (int rt = 0; rt < 4; ++rt) {
#pragma unroll
        for (int r = 0; r < 4; ++r) {
            int row = row0 + rt * 16 + quad * 4 + r;
            float c0 = acc[rt][0][r], c1 = acc[rt][1][r];
            float m = fmaxf(fabsf(c0), fabsf(c1));
            m = fmaxf(m, __shfl_xor(m, 1));
            m = fmaxf(m, __shfl_xor(m, 2));
            m = fmaxf(m, __shfl_xor(m, 4));
            m = fmaxf(m, __shfl_xor(m, 8));
            m = fmaxf(m, 1e-20f);
            float qsc = 127.0f / m;
            if (row < n) {
                hq[(size_t)row * 128 + wave * 32 + l15] = (signed char)(int)rintf(c0 * qsc);
                hq[(size_t)row * 128 + wave * 32 + 16 + l15] = (signed char)(int)rintf(c1 * qsc);
            }
            float pel = c0 * alv0 + c1 * alv1;
            float per = c0 * arv0 + c1 * arv1;
            pel += __shfl_xor(pel, 1); pel += __shfl_xor(pel, 2);
            pel += __shfl_xor(pel, 4); pel += __shfl_xor(pel, 8);
            per += __shfl_xor(per, 1); per += __shfl_xor(per, 2);
            per += __shfl_xor(per, 4); per += __shfl_xor(per, 8);
            if (l15 == 0 && row < n) {
                elhs[row * 4 + wave] = make_float2(pel, m * (1.0f / 127.0f));
                er[row * 4 + wave] = per;
            }
        }
    }
}

// ---------------- MFMA GEMM (layer 2, bf16 input from h1) ----------------
template <int BF16IN>
__global__ __launch_bounds__(256) void gemm_mfma(
    const void* __restrict__ Xv, const u16* __restrict__ Wp,
    const float* __restrict__ al, const float* __restrict__ ar,
    signed char* __restrict__ hq, float2* __restrict__ elhs, float* __restrict__ er, int n)
{
    __shared__ u16 xs[64][136];   // +8 pad: 2-way LDS bank aliasing (free)
    int row0 = blockIdx.x * 64;
    int tid = threadIdx.x;
    if (BF16IN) {
        const uint4* Xb = (const uint4*)Xv;
        for (int i = tid; i < 1024; i += 256) {
            int r = i >> 4, c = i & 15;
            uint4 v = make_uint4(0u, 0u, 0u, 0u);
            if (row0 + r < n) v = Xb[(size_t)(row0 + r) * 16 + c];
            ((uint4*)&xs[r][0])[c] = v;
        }
    } else {
        const float4* X4 = (const float4*)Xv;
        for (int i = tid; i < 2048; i += 256) {
            int r = i >> 5, c = i & 31;
            float4 v = make_float4(0.f, 0.f, 0.f, 0.f);
            if (row0 + r < n) v = X4[(size_t)(row0 + r) * 32 + c];
            ((uint2*)&xs[r][0])[c] = make_uint2(pack2(v.x, v.y), pack2(v.z, v.w));
        }
    }
    __syncthreads();

    int wave = tid >> 6, lane = tid & 63;
    int quad = lane >> 4, l15 = lane & 15;

    bf16x8 bfrag[2][4];
#pragma unroll
    for (int ct = 0; ct < 2; ++ct) {
        int nt = wave * 2 + ct;
#pragma unroll
        for (int ks = 0; ks < 4; ++ks)
            bfrag[ct][ks] = *(const bf16x8*)(Wp + ((((nt * 4 + ks) * 64) + lane) << 3));
    }

    f32x4 acc[4][2];
#pragma unroll
    for (int rt = 0; rt < 4; ++rt)
#pragma unroll
        for (int ct = 0; ct < 2; ++ct)
            acc[rt][ct] = (f32x4){0.f, 0.f, 0.f, 0.f};

#pragma unroll
    for (int ks = 0; ks < 4; ++ks) {
#pragma unroll
        for (int rt = 0; rt < 4; ++rt) {
            bf16x8 a = *(const bf16x8*)&xs[rt * 16 + l15][ks * 32 + quad * 8];
            acc[rt][0] = __builtin_amdgcn_mfma_f32_16x16x32_bf16(a, bfrag[0][ks], acc[rt][0], 0, 0, 0);
            acc[rt][1] = __builtin_amdgcn_mfma_f32_16x16x32_bf16(a, bfrag[1][ks], acc[rt][1], 0, 0, 0);
        }
    }

    float alv0 = al[wave * 32 + l15], alv1 = al[wave * 32 + 16 + l15];
    float arv0 = ar[wave * 32 + l15], arv1 = ar[wave * 32 + 16 + l15];
#pragma unroll
    for (int rt = 0; rt < 4; ++rt) {
#pragma unroll
        for (int r = 0; r < 4; ++r) {
            int row = row0 + rt * 16 + quad * 4 + r;
            float c0 = acc[rt][0][r], c1 = acc[rt][1][r];
            // per-(row, head) absmax over the wave's 32 cols (reduce over l15 lanes)
            float m = fmaxf(fabsf(c0), fabsf(c1));
            m = fmaxf(m, __shfl_xor(m, 1));
            m = fmaxf(m, __shfl_xor(m, 2));
            m = fmaxf(m, __shfl_xor(m, 4));
            m = fmaxf(m, __shfl_xor(m, 8));
            m = fmaxf(m, 1e-20f);
            float qsc = 127.0f / m;
            if (row < n) {
                hq[(size_t)row * 128 + wave * 32 + l15] = (signed char)(int)rintf(c0 * qsc);
                hq[(size_t)row * 128 + wave * 32 + 16 + l15] = (signed char)(int)rintf(c1 * qsc);
            }
            float pel = c0 * alv0 + c1 * alv1;
            float per = c0 * arv0 + c1 * arv1;
            pel += __shfl_xor(pel, 1); pel += __shfl_xor(pel, 2);
            pel += __shfl_xor(pel, 4); pel += __shfl_xor(pel, 8);
            per += __shfl_xor(per, 1); per += __shfl_xor(per, 2);
            per += __shfl_xor(per, 4); per += __shfl_xor(per, 8);
            if (l15 == 0 && row < n) {
                elhs[row * 4 + wave] = make_float2(pel, m * (1.0f / 127.0f));
                er[row * 4 + wave] = per;
            }
        }
    }
}

// ---------------- agg core: quarter-wave per edge, lane owns 8 int8 features (uint2) ---------
// Two gather streams per edge: elhs (8B) + hq (8B). srcs preloaded via one coalesced load+shfl.
static __device__ __forceinline__ void agg_core(
    int node, int lane, const int2* __restrict__ offs2, const u16* __restrict__ srcs,
    const float2* __restrict__ elhs, const float* __restrict__ er,
    const signed char* __restrict__ hq,
    float acc[8], float& den)
{
    int qw = lane >> 4;
    int q = lane & 15;
    int h = q >> 2;
    float erh = er[node * 4 + h];
    int2 be = offs2[node];
    int beg = be.x, end = be.y;
    int deg = end - beg;
    den = 0.f;
#pragma unroll
    for (int i = 0; i < 8; i++) acc[i] = 0.f;

    if (deg <= 64) {
        int psrc = (lane < deg) ? (int)srcs[beg + lane] : 0;
        int base = beg;
        for (; base + 16 <= end; base += 16) {
            int j = base - beg + qw;
            int ss[4];
            ss[0] = __shfl(psrc, j);
            ss[1] = __shfl(psrc, j + 4);
            ss[2] = __shfl(psrc, j + 8);
            ss[3] = __shfl(psrc, j + 12);
            float2 eh[4];
            uint2 uv[4];
#pragma unroll
            for (int k = 0; k < 4; ++k) {
                eh[k] = elhs[ss[k] * 4 + h];
                uv[k] = *(const uint2*)(hq + (size_t)ss[k] * 128 + q * 8);
            }
#pragma unroll
            for (int k = 0; k < 4; ++k) {
                float w = __expf(lrelu(eh[k].x + erh));
                float ws = w * eh[k].y;
                den += w;
                acc[0] += ws * sx(uv[k].x, 0);
                acc[1] += ws * sx(uv[k].x, 1);
                acc[2] += ws * sx(uv[k].x, 2);
                acc[3] += ws * sx(uv[k].x, 3);
                acc[4] += ws * sx(uv[k].y, 0);
                acc[5] += ws * sx(uv[k].y, 1);
                acc[6] += ws * sx(uv[k].y, 2);
                acc[7] += ws * sx(uv[k].y, 3);
            }
        }
        for (; base + 8 <= end; base += 8) {
            int j = base - beg + qw;
            int s0 = __shfl(psrc, j);
            int s1 = __shfl(psrc, j + 4);
            float2 e0 = elhs[s0 * 4 + h], e1 = elhs[s1 * 4 + h];
            uint2 u0 = *(const uint2*)(hq + (size_t)s0 * 128 + q * 8);
            uint2 u1 = *(const uint2*)(hq + (size_t)s1 * 128 + q * 8);
            float w0 = __expf(lrelu(e0.x + erh));
            float w1 = __expf(lrelu(e1.x + erh));
            float ws0 = w0 * e0.y, ws1 = w1 * e1.y;
            den += w0 + w1;
            acc[0] += ws0 * sx(u0.x, 0) + ws1 * sx(u1.x, 0);
            acc[1] += ws0 * sx(u0.x, 1) + ws1 * sx(u1.x, 1);
            acc[2] += ws0 * sx(u0.x, 2) + ws1 * sx(u1.x, 2);
            acc[3] += ws0 * sx(u0.x, 3) + ws1 * sx(u1.x, 3);
            acc[4] += ws0 * sx(u0.y, 0) + ws1 * sx(u1.y, 0);
            acc[5] += ws0 * sx(u0.y, 1) + ws1 * sx(u1.y, 1);
            acc[6] += ws0 * sx(u0.y, 2) + ws1 * sx(u1.y, 2);
            acc[7] += ws0 * sx(u0.y, 3) + ws1 * sx(u1.y, 3);
        }
        for (; base < end; base += 4) {
            int e = base + qw;
            bool valid = e < end;
            int j = valid ? (e - beg) : 0;
            int s = __shfl(psrc, j);
            float2 eh = elhs[s * 4 + h];
            float w = valid ? __expf(lrelu(eh.x + erh)) : 0.f;
            float ws = w * eh.y;
            uint2 u = *(const uint2*)(hq + (size_t)s * 128 + q * 8);
            den += w;
            acc[0] += ws * sx(u.x, 0);
            acc[1] += ws * sx(u.x, 1);
            acc[2] += ws * sx(u.x, 2);
            acc[3] += ws * sx(u.x, 3);
            acc[4] += ws * sx(u.y, 0);
            acc[5] += ws * sx(u.y, 1);
            acc[6] += ws * sx(u.y, 2);
            acc[7] += ws * sx(u.y, 3);
        }
    } else {
        for (int base = beg; base < end; base += 4) {
            int e = base + qw;
            bool valid = e < end;
            int ec = valid ? e : end - 1;
            int s = srcs[ec];
            float2 eh = elhs[s * 4 + h];
            float w = valid ? __expf(lrelu(eh.x + erh)) : 0.f;
            float ws = w * eh.y;
            uint2 u = *(const uint2*)(hq + (size_t)s * 128 + q * 8);
            den += w;
            acc[0] += ws * sx(u.x, 0);
            acc[1] += ws * sx(u.x, 1);
            acc[2] += ws * sx(u.x, 2);
            acc[3] += ws * sx(u.x, 3);
            acc[4] += ws * sx(u.y, 0);
            acc[5] += ws * sx(u.y, 1);
            acc[6] += ws * sx(u.y, 2);
            acc[7] += ws * sx(u.y, 3);
        }
    }
#pragma unroll
    for (int i = 0; i < 8; i++) {
        acc[i] += __shfl_xor(acc[i], 16);
        acc[i] += __shfl_xor(acc[i], 32);
    }
    den += __shfl_xor(den, 16);
    den += __shfl_xor(den, 32);
}

// ---------------- layer-1 aggregation (relu, bf16 out node-major) ----------------
__global__ __launch_bounds__(256) void agg1_k(const int2* __restrict__ offs2, const u16* __restrict__ srcs,
                                              const float2* __restrict__ elhs, const float* __restrict__ er,
                                              const signed char* __restrict__ hq,
                                              const float* __restrict__ bias, u16* __restrict__ h1) {
    int node = blockIdx.x * 4 + (threadIdx.x >> 6);
    int lane = threadIdx.x & 63;
    if (node >= N_NODES) return;
    float acc[8], den;
    agg_core(node, lane, offs2, srcs, elhs, er, hq, acc, den);
    int qw = lane >> 4, q = lane & 15;
    if (qw == 0) {
        float inv = 1.0f / fmaxf(den, 1e-30f);
        float o[8];
#pragma unroll
        for (int i = 0; i < 8; i++)
            o[i] = fmaxf(acc[i] * inv + bias[q * 8 + i], 0.f);
        uint4 pk;
        pk.x = pack2(o[0], o[1]);
        pk.y = pack2(o[2], o[3]);
        pk.z = pack2(o[4], o[5]);
        pk.w = pack2(o[6], o[7]);
        *(uint4*)(h1 + (size_t)node * 128 + q * 8) = pk;
    }
}

// ---------------- layer-2 aggregation fused with head-mean/relu/proj/softmax ----------------
__global__ __launch_bounds__(256) void agg2_k(const int2* __restrict__ offs2, const u16* __restrict__ srcs,
                                              const float2* __restrict__ elhs, const float* __restrict__ er,
                                              const signed char* __restrict__ hq,
                                              const float* __restrict__ bias,
                                              const float* __restrict__ Wout, const float* __restrict__ bout,
                                              float2* __restrict__ out) {
    int node = blockIdx.x * 4 + (threadIdx.x >> 6);
    int lane = threadIdx.x & 63;
    if (node >= N_NODES) return;
    float acc[8], den;
    agg_core(node, lane, offs2, srcs, elhs, er, hq, acc, den);
    int q = lane & 15;
    float inv = 1.0f / fmaxf(den, 1e-30f);
    float o[8];
#pragma unroll
    for (int i = 0; i < 8; i++) o[i] = acc[i] * inv + bias[q * 8 + i];
    // mean over heads (head = lane bits 2,3), then relu
#pragma unroll
    for (int i = 0; i < 8; i++) {
        o[i] += __shfl_xor(o[i], 4);
        o[i] += __shfl_xor(o[i], 8);
        o[i] = fmaxf(0.25f * o[i], 0.f);
    }
    int d0 = (q & 3) * 8;
    float l0 = 0.f, l1 = 0.f;
#pragma unroll
    for (int i = 0; i < 8; i++) {
        l0 += o[i] * Wout[(d0 + i) * 2];
        l1 += o[i] * Wout[(d0 + i) * 2 + 1];
    }
    l0 += __shfl_xor(l0, 1); l0 += __shfl_xor(l0, 2);
    l1 += __shfl_xor(l1, 1); l1 += __shfl_xor(l1, 2);
    if (lane == 0) {
        l0 += bout[0];
        l1 += bout[1];
        float mx = fmaxf(l0, l1);
        float e0 = __expf(l0 - mx), e1 = __expf(l1 - mx);
        float invs = 1.f / (e0 + e1);
        out[node] = make_float2(e0 * invs, e1 * invs);
    }
}

extern "C" void kernel_launch(void* const* d_in, const int* in_sizes, int n_in,
                              void* d_out, int out_size, void* d_ws, size_t ws_size,
                              hipStream_t stream) {
    const float* in_feat = (const float*)d_in[0];
    const float* W1   = (const float*)d_in[1];
    const float* al1  = (const float*)d_in[2];
    const float* ar1  = (const float*)d_in[3];
    const float* b1   = (const float*)d_in[4];
    const float* W2   = (const float*)d_in[5];
    const float* al2  = (const float*)d_in[6];
    const float* ar2  = (const float*)d_in[7];
    const float* b2   = (const float*)d_in[8];
    const float* Wout = (const float*)d_in[9];
    const float* bout = (const float*)d_in[10];
    const int*   src  = (const int*)d_in[11];
    const int*   dst  = (const int*)d_in[12];
    float* out = (float*)d_out;

    char* ws = (char*)d_ws;
    size_t off = 0;
    auto carve = [&](size_t bytes) {
        char* p = ws + off;
        off = (off + bytes + 255) & ~(size_t)255;
        return p;
    };
    signed char* hq  = (signed char*)carve((size_t)N_NODES * 128);   // int8 features
    float2* elhs     = (float2*)carve((size_t)N_NODES * 4 * 8);      // {el, scale} per (node, head)
    u16*   h1        = (u16*)carve((size_t)N_NODES * 128 * 2);       // layer-1 output (bf16)
    float* er        = (float*)carve((size_t)N_NODES * 4 * 4);
    u16*   srcs      = (u16*)carve((size_t)NBUCK * CAP * 2);         // padded per-bucket srcs
    u32*   bucketed  = (u32*)carve((size_t)NBUCK * CAP * 4);         // padded per-bucket edges
    u32*   gpos      = (u32*)carve((size_t)NBUCK * 4);
    int2*  offs2     = (int2*)carve((size_t)N_NODES * 8);            // {beg, end} per node
    u16*   Wp1       = (u16*)carve((size_t)16384 * 2);
    u16*   Wp2       = (u16*)carve((size_t)16384 * 2);
    (void)ws_size; (void)in_sizes; (void)n_in; (void)out_size;

    const int SB = (N_EDGES + EPB - 1) / EPB;    // 196 scatter blocks
    const int GB = (N_NODES + 63) / 64;          // 782
    const int AB = (N_NODES + 3) / 4;            // 12500

    // D1: weight pre-pack + gpos zero
    pack_zero_k<<<33, 1024, 0, stream>>>(W1, W2, Wp1, Wp2, gpos);
    // D2: one-pass scatter with atomic bucket reservation
    bscatter2_k<<<SB, 1024, 0, stream>>>(src, dst, gpos, bucketed);
    // D3: fine CSR + layer-1 GEMM overlapped (proven round-5 pairing)
    bcsr_gemm1_k<<<NBUCK + GB, 256, 0, stream>>>(bucketed, gpos, offs2, srcs,
                                                 in_feat, Wp1, al1, ar1, hq, elhs, er, N_NODES);
    // D4: layer-1 aggregation
    agg1_k<<<AB, 256, 0, stream>>>(offs2, srcs, elhs, er, hq, b1, h1);
    // D5: layer-2 GEMM (reuses hq/elhs/er in place)
    gemm_mfma<1><<<GB, 256, 0, stream>>>(h1, Wp2, al2, ar2, hq, elhs, er, N_NODES);
    // D6: layer-2 aggregation + head-mean/relu/proj/softmax
    agg2_k<<<AB, 256, 0, stream>>>(offs2, srcs, elhs, er, hq, b2, Wout, bout, (float2*)out);
}